// Round 1
// baseline (552.870 us; speedup 1.0000x reference)
//
#include <hip/hip_runtime.h>
#include <math.h>

#define BB 8
#define NN 2048
#define SS 16
#define CC 32
#define DD 128

// ---------------- K1: masked temporal mean pooling ----------------
// x[b,n,c] = sum_s X[b,n,s,c]*m[b,n,s] / max(sum_s m, 1)
__global__ __launch_bounds__(256) void pool_kernel(const float* __restrict__ X,
                                                   const float* __restrict__ M,
                                                   float* __restrict__ x) {
    int g = blockIdx.x * 256 + threadIdx.x;       // over B*N*C = 524288
    int c = g & (CC - 1);
    int bn = g >> 5;
    const float* mrow = M + (size_t)bn * SS;
    const float* xrow = X + (size_t)bn * SS * CC + c;
    float msum = 0.f, acc = 0.f;
#pragma unroll
    for (int s = 0; s < SS; ++s) {
        float mv = mrow[s];
        msum += mv;
        acc = fmaf(xrow[s * CC], mv, acc);
    }
    x[g] = acc / fmaxf(msum, 1.0f);
}

// ---------------- K2: fold projections: Wpq = W_proj@Wq, Wpk = W_proj@Wk ----
__global__ __launch_bounds__(256) void wcomb_kernel(const float* __restrict__ Wproj,
                                                    const float* __restrict__ Wq,
                                                    const float* __restrict__ Wk,
                                                    float* __restrict__ Wpq,
                                                    float* __restrict__ Wpk) {
    int g = blockIdx.x * 256 + threadIdx.x;       // over 2*32*128 = 8192
    int d = g & 127;
    int c = (g >> 7) & 31;
    int mat = g >> 12;
    const float* Wt = mat ? Wk : Wq;
    float acc = 0.f;
#pragma unroll 4
    for (int e = 0; e < DD; ++e)
        acc = fmaf(Wproj[c * DD + e], Wt[e * DD + d], acc);
    (mat ? Wpk : Wpq)[c * DD + d] = acc;
}

// ---------------- K3: Hn = x@W_proj, Q = x@Wpq, K = x@Wpk (K-dim = 32) ------
__global__ __launch_bounds__(256) void proj3_kernel(const float* __restrict__ x,
                                                    const float* __restrict__ Wproj,
                                                    const float* __restrict__ Wpq,
                                                    const float* __restrict__ Wpk,
                                                    float* __restrict__ Hn,
                                                    float* __restrict__ Q,
                                                    float* __restrict__ Km) {
    __shared__ float wp[CC * DD], wq[CC * DD], wk[CC * DD];
    __shared__ float xs[CC * 36];                 // k-major x tile: xs[k*36 + row]
    int t = threadIdx.x;
    for (int i = t; i < CC * DD; i += 256) {
        wp[i] = Wproj[i];
        wq[i] = Wpq[i];
        wk[i] = Wpk[i];
    }
    int rbase = blockIdx.x * 32;
    for (int i = t; i < 32 * CC; i += 256) {
        int row = i >> 5, c = i & 31;
        xs[c * 36 + row] = x[(size_t)(rbase + row) * CC + c];
    }
    __syncthreads();

    int col = t & 127;
    int g = t >> 7;                               // 0..1, rows g*16 .. g*16+15
    float ah[16], aq[16], ak[16];
#pragma unroll
    for (int i = 0; i < 16; ++i) { ah[i] = 0.f; aq[i] = 0.f; ak[i] = 0.f; }

#pragma unroll 4
    for (int k = 0; k < CC; ++k) {
        float wpv = wp[k * DD + col], wqv = wq[k * DD + col], wkv = wk[k * DD + col];
        const float4* xp = (const float4*)&xs[k * 36 + g * 16];
        float4 a0 = xp[0], a1 = xp[1], a2 = xp[2], a3 = xp[3];
        float xv[16] = {a0.x, a0.y, a0.z, a0.w, a1.x, a1.y, a1.z, a1.w,
                        a2.x, a2.y, a2.z, a2.w, a3.x, a3.y, a3.z, a3.w};
#pragma unroll
        for (int i = 0; i < 16; ++i) {
            ah[i] = fmaf(xv[i], wpv, ah[i]);
            aq[i] = fmaf(xv[i], wqv, aq[i]);
            ak[i] = fmaf(xv[i], wkv, ak[i]);
        }
    }
#pragma unroll
    for (int i = 0; i < 16; ++i) {
        size_t row = (size_t)(rbase + g * 16 + i);
        Hn[row * DD + col] = ah[i];
        Q[row * DD + col] = aq[i];
        Km[row * DD + col] = ak[i];
    }
}

// ---------------- K4: raw scaled logits = (Q_b @ K_b^T)/sqrt(D) ------------
// Writes into the A_fuse output region; bias/mask/softmax applied by K5.
__global__ __launch_bounds__(256) void qk_kernel(const float* __restrict__ Q,
                                                 const float* __restrict__ Km,
                                                 float* __restrict__ Afuse) {
    int b = blockIdx.z;
    int rb = blockIdx.y * 64;
    int cb = blockIdx.x * 64;
    __shared__ float Qt[32 * 68], Kt[32 * 68];    // k-major: [kk*68 + row]
    int t = threadIdx.x;
    int tx = t & 15, ty = t >> 4;
    float acc[4][4] = {};
    const float* Qb = Q + (size_t)b * NN * DD;
    const float* Kb = Km + (size_t)b * NN * DD;

    for (int kc = 0; kc < DD; kc += 32) {
        __syncthreads();
#pragma unroll
        for (int i = 0; i < 8; ++i) {
            int idx = i * 256 + t;
            int row = idx >> 5, kk = idx & 31;
            Qt[kk * 68 + row] = Qb[(size_t)(rb + row) * DD + kc + kk];
            Kt[kk * 68 + row] = Kb[(size_t)(cb + row) * DD + kc + kk];
        }
        __syncthreads();
#pragma unroll
        for (int kk = 0; kk < 32; ++kk) {
            float4 av = *(const float4*)&Qt[kk * 68 + ty * 4];
            float4 bv = *(const float4*)&Kt[kk * 68 + tx * 4];
            float av4[4] = {av.x, av.y, av.z, av.w};
            float bv4[4] = {bv.x, bv.y, bv.z, bv.w};
#pragma unroll
            for (int r = 0; r < 4; ++r)
#pragma unroll
                for (int c = 0; c < 4; ++c)
                    acc[r][c] = fmaf(av4[r], bv4[c], acc[r][c]);
        }
    }
    const float scale = 0.08838834764831845f;     // 1/sqrt(128)
    float* Ab = Afuse + (size_t)b * NN * NN;
#pragma unroll
    for (int r = 0; r < 4; ++r) {
        float4 o = make_float4(acc[r][0] * scale, acc[r][1] * scale,
                               acc[r][2] * scale, acc[r][3] * scale);
        *(float4*)&Ab[(size_t)(rb + ty * 4 + r) * NN + cb + tx * 4] = o;
    }
}

// ---------------- K5: per-row bias + mask + softmax + fuse + renormalize ----
__global__ __launch_bounds__(256) void rowfuse_kernel(float* __restrict__ Afuse,
                                                      const float* __restrict__ Astat,
                                                      const int* __restrict__ Mm,
                                                      const float* __restrict__ rel) {
    __shared__ float red[4];
    int bn = blockIdx.x;                          // b*N + n
    int b = bn >> 11;
    int n = bn & (NN - 1);
    int t = threadIdx.x;
    float* Arow = Afuse + (size_t)bn * NN;
    const float* Asrow = Astat + (size_t)n * NN;
    const int* Mrow = Mm + (size_t)n * NN;
    float rn = fminf(fmaxf(rel[bn], 0.f), 1.f);

    float l[8], as[8], rm[8];
    int eg[8];
    float lmax = -1e30f;
#pragma unroll
    for (int i = 0; i < 8; ++i) {
        int m = i * 256 + t;
        float dot = Arow[m];                      // already scaled by 1/sqrt(D)
        float a = Asrow[m];
        as[i] = a;
        int e = Mrow[m];
        eg[i] = e;
        float p = fminf(fmaxf(a, 1e-3f), 1.f - 1e-3f);
        float lg = __logf(p / (1.f - p));         // ETA = 1.0
        l[i] = e ? (dot + lg) : -1e30f;
        lmax = fmaxf(lmax, l[i]);
        rm[i] = fminf(fmaxf(rel[b * NN + m], 0.f), 1.f);
    }
    // block max
    float v = lmax;
#pragma unroll
    for (int off = 32; off; off >>= 1) v = fmaxf(v, __shfl_down(v, off));
    if ((t & 63) == 0) red[t >> 6] = v;
    __syncthreads();
    float mx = fmaxf(fmaxf(red[0], red[1]), fmaxf(red[2], red[3]));
    __syncthreads();
    // expsum
    float e_[8];
    float esum = 0.f;
#pragma unroll
    for (int i = 0; i < 8; ++i) {
        e_[i] = eg[i] ? __expf(l[i] - mx) : 0.f;
        esum += e_[i];
    }
    v = esum;
#pragma unroll
    for (int off = 32; off; off >>= 1) v += __shfl_down(v, off);
    if ((t & 63) == 0) red[t >> 6] = v;
    __syncthreads();
    float sm = red[0] + red[1] + red[2] + red[3];
    __syncthreads();
    float inv = 1.f / sm;
    // fuse + reliability + mask
    float val[8];
    float fsum = 0.f;
#pragma unroll
    for (int i = 0; i < 8; ++i) {
        val[i] = eg[i] ? (0.6f * e_[i] * inv + 0.4f * as[i]) * rn * rm[i] : 0.f;
        fsum += val[i];
    }
    v = fsum;
#pragma unroll
    for (int off = 32; off; off >>= 1) v += __shfl_down(v, off);
    if ((t & 63) == 0) red[t >> 6] = v;
    __syncthreads();
    float fs = red[0] + red[1] + red[2] + red[3];
    float norm = 1.f / (fs + 1e-8f);
#pragma unroll
    for (int i = 0; i < 8; ++i)
        Arow[i * 256 + t] = val[i] * norm;
}

// ---------------- K6/K7: generic NN GEMM, 64x64 tile, 4x4 micro ------------
// C[rb+r][cb+c] = sum_k A[r][k] * B[k][c];  ldb = ldc = 128
__global__ __launch_bounds__(256) void gemm_nn_kernel(const float* __restrict__ A,
                                                      const float* __restrict__ Bm,
                                                      float* __restrict__ Cm,
                                                      int K, long long sA, long long sB,
                                                      long long sC, int lda) {
    int b = blockIdx.z;
    const float* Ab = A + (size_t)b * sA;
    const float* Bb = Bm + (size_t)b * sB;
    float* Cb = Cm + (size_t)b * sC;
    int rb = blockIdx.y * 64;
    int cb = blockIdx.x * 64;
    __shared__ float At[32 * 68], Bt[32 * 68];    // k-major: [kk*68 + row/col]
    int t = threadIdx.x;
    int tx = t & 15, ty = t >> 4;
    float acc[4][4] = {};

    for (int kc = 0; kc < K; kc += 32) {
        __syncthreads();
#pragma unroll
        for (int i = 0; i < 8; ++i) {
            int idx = i * 256 + t;
            {
                int row = idx >> 5, kk = idx & 31;
                At[kk * 68 + row] = Ab[(size_t)(rb + row) * lda + kc + kk];
            }
            {
                int kk = idx >> 6, col = idx & 63;
                Bt[kk * 68 + col] = Bb[(size_t)(kc + kk) * DD + cb + col];
            }
        }
        __syncthreads();
#pragma unroll
        for (int kk = 0; kk < 32; ++kk) {
            float4 av = *(const float4*)&At[kk * 68 + ty * 4];
            float4 bv = *(const float4*)&Bt[kk * 68 + tx * 4];
            float av4[4] = {av.x, av.y, av.z, av.w};
            float bv4[4] = {bv.x, bv.y, bv.z, bv.w};
#pragma unroll
            for (int r = 0; r < 4; ++r)
#pragma unroll
                for (int c = 0; c < 4; ++c)
                    acc[r][c] = fmaf(av4[r], bv4[c], acc[r][c]);
        }
    }
#pragma unroll
    for (int r = 0; r < 4; ++r) {
        float4 o = make_float4(acc[r][0], acc[r][1], acc[r][2], acc[r][3]);
        *(float4*)&Cb[(size_t)(rb + ty * 4 + r) * DD + cb + tx * 4] = o;
    }
}

// ---------------- K8: relu -> LN1 -> LN2 -----------------------------------
__global__ __launch_bounds__(128) void ln_kernel(const float* __restrict__ Hin,
                                                 const float* __restrict__ s1,
                                                 const float* __restrict__ b1,
                                                 const float* __restrict__ s2,
                                                 const float* __restrict__ b2,
                                                 float* __restrict__ out) {
    __shared__ float red[2];
    int row = blockIdx.x;
    int d = threadIdx.x;
    float v = fmaxf(Hin[(size_t)row * DD + d], 0.f);

    auto rsum = [&](float xv) {
#pragma unroll
        for (int off = 32; off; off >>= 1) xv += __shfl_down(xv, off);
        if ((threadIdx.x & 63) == 0) red[threadIdx.x >> 6] = xv;
        __syncthreads();
        float tot = red[0] + red[1];
        __syncthreads();
        return tot;
    };

    float mu = rsum(v) * (1.f / 128.f);
    float dv = v - mu;
    float var = rsum(dv * dv) * (1.f / 128.f);
    float y = dv * (1.f / sqrtf(var + 1e-5f)) * s1[d] + b1[d];
    float mu2 = rsum(y) * (1.f / 128.f);
    float dy = y - mu2;
    float var2 = rsum(dy * dy) * (1.f / 128.f);
    out[(size_t)row * DD + d] = dy * (1.f / sqrtf(var2 + 1e-5f)) * s2[d] + b2[d];
}

extern "C" void kernel_launch(void* const* d_in, const int* in_sizes, int n_in,
                              void* d_out, int out_size, void* d_ws, size_t ws_size,
                              hipStream_t stream) {
    const float* X = (const float*)d_in[0];
    const float* Msk = (const float*)d_in[1];
    const float* Astat = (const float*)d_in[2];
    const int* Mm = (const int*)d_in[3];
    const float* rel = (const float*)d_in[4];
    const float* Wproj = (const float*)d_in[5];
    const float* Wq = (const float*)d_in[6];
    const float* Wk = (const float*)d_in[7];
    const float* Wlin = (const float*)d_in[8];
    const float* s1 = (const float*)d_in[9];
    const float* b1 = (const float*)d_in[10];
    const float* s2 = (const float*)d_in[11];
    const float* b2 = (const float*)d_in[12];

    float* outMain = (float*)d_out;                       // (B,N,D) = 2097152
    float* Afuse = outMain + (size_t)BB * NN * DD;        // (B,N,N) = 33554432

    float* w = (float*)d_ws;
    float* x = w;                                         // 524288
    float* Hn = w + 524288;                               // 2097152
    float* Q = w + 2621440;                               // 2097152
    float* Km = w + 4718592;                              // 2097152
    float* Wpq = w + 6815744;                             // 4096
    float* Wpk = w + 6819840;                             // 4096
    float* H = Q;                                         // reuse (Q dead after qk)
    float* H2 = Km;                                       // reuse (Km dead after qk)

    pool_kernel<<<dim3(2048), dim3(256), 0, stream>>>(X, Msk, x);
    wcomb_kernel<<<dim3(32), dim3(256), 0, stream>>>(Wproj, Wq, Wk, Wpq, Wpk);
    proj3_kernel<<<dim3(512), dim3(256), 0, stream>>>(x, Wproj, Wpq, Wpk, Hn, Q, Km);
    qk_kernel<<<dim3(32, 32, 8), dim3(256), 0, stream>>>(Q, Km, Afuse);
    rowfuse_kernel<<<dim3(16384), dim3(256), 0, stream>>>(Afuse, Astat, Mm, rel);
    gemm_nn_kernel<<<dim3(2, 32, 8), dim3(256), 0, stream>>>(
        Afuse, Hn, H, NN, (long long)NN * NN, (long long)NN * DD, (long long)NN * DD, NN);
    gemm_nn_kernel<<<dim3(2, 256, 1), dim3(256), 0, stream>>>(
        H, Wlin, H2, DD, 0LL, 0LL, 0LL, DD);
    ln_kernel<<<dim3(16384), dim3(128), 0, stream>>>(H2, s1, b1, s2, b2, outMain);
}

// Round 2
// 395.214 us; speedup vs baseline: 1.3989x; 1.3989x over previous
//
#include <hip/hip_runtime.h>
#include <math.h>

#define BB 8
#define NN 2048
#define SS 16
#define CC 32
#define DD 128

typedef unsigned short u16;
typedef __attribute__((ext_vector_type(8))) short bf16x8;
typedef __attribute__((ext_vector_type(4))) float f32x4;

__device__ inline u16 f2bf(float f) {
    union { float f; unsigned u; } c; c.f = f;
    unsigned r = c.u + 0x7fff + ((c.u >> 16) & 1);   // round-to-nearest-even
    return (u16)(r >> 16);
}

// ---------------- K1: masked temporal mean pooling ----------------
__global__ __launch_bounds__(256) void pool_kernel(const float* __restrict__ X,
                                                   const float* __restrict__ M,
                                                   float* __restrict__ x) {
    int g = blockIdx.x * 256 + threadIdx.x;       // over B*N*C = 524288
    int c = g & (CC - 1);
    int bn = g >> 5;
    const float* mrow = M + (size_t)bn * SS;
    const float* xrow = X + (size_t)bn * SS * CC + c;
    float msum = 0.f, acc = 0.f;
#pragma unroll
    for (int s = 0; s < SS; ++s) {
        float mv = mrow[s];
        msum += mv;
        acc = fmaf(xrow[s * CC], mv, acc);
    }
    x[g] = acc / fmaxf(msum, 1.0f);
}

// ---------------- K2: fold projections: Wpq = W_proj@Wq, Wpk = W_proj@Wk ----
__global__ __launch_bounds__(256) void wcomb_kernel(const float* __restrict__ Wproj,
                                                    const float* __restrict__ Wq,
                                                    const float* __restrict__ Wk,
                                                    float* __restrict__ Wpq,
                                                    float* __restrict__ Wpk) {
    int g = blockIdx.x * 256 + threadIdx.x;       // over 2*32*128 = 8192
    int d = g & 127;
    int c = (g >> 7) & 31;
    int mat = g >> 12;
    const float* Wt = mat ? Wk : Wq;
    float acc = 0.f;
#pragma unroll 4
    for (int e = 0; e < DD; ++e)
        acc = fmaf(Wproj[c * DD + e], Wt[e * DD + d], acc);
    (mat ? Wpk : Wpq)[c * DD + d] = acc;
}

// ---------------- K3: Hn/Q/K in fp32, emitted as bf16 (Q,K row-major; Hn^T) -
__global__ __launch_bounds__(256) void proj3_kernel(const float* __restrict__ x,
                                                    const float* __restrict__ Wproj,
                                                    const float* __restrict__ Wpq,
                                                    const float* __restrict__ Wpk,
                                                    u16* __restrict__ HnT,
                                                    u16* __restrict__ Qb,
                                                    u16* __restrict__ Kb) {
    __shared__ float wp[CC * DD], wq[CC * DD], wk[CC * DD];
    __shared__ float xs[CC * 36];                 // k-major x tile: xs[k*36 + row]
    int t = threadIdx.x;
    for (int i = t; i < CC * DD; i += 256) {
        wp[i] = Wproj[i];
        wq[i] = Wpq[i];
        wk[i] = Wpk[i];
    }
    int rbase = blockIdx.x * 32;
    for (int i = t; i < 32 * CC; i += 256) {
        int row = i >> 5, c = i & 31;
        xs[c * 36 + row] = x[(size_t)(rbase + row) * CC + c];
    }
    __syncthreads();

    int col = t & 127;
    int g = t >> 7;                               // 0..1, rows g*16 .. g*16+15
    float ah[16], aq[16], ak[16];
#pragma unroll
    for (int i = 0; i < 16; ++i) { ah[i] = 0.f; aq[i] = 0.f; ak[i] = 0.f; }

#pragma unroll 4
    for (int k = 0; k < CC; ++k) {
        float wpv = wp[k * DD + col], wqv = wq[k * DD + col], wkv = wk[k * DD + col];
        const float4* xp = (const float4*)&xs[k * 36 + g * 16];
        float4 a0 = xp[0], a1 = xp[1], a2 = xp[2], a3 = xp[3];
        float xv[16] = {a0.x, a0.y, a0.z, a0.w, a1.x, a1.y, a1.z, a1.w,
                        a2.x, a2.y, a2.z, a2.w, a3.x, a3.y, a3.z, a3.w};
#pragma unroll
        for (int i = 0; i < 16; ++i) {
            ah[i] = fmaf(xv[i], wpv, ah[i]);
            aq[i] = fmaf(xv[i], wqv, aq[i]);
            ak[i] = fmaf(xv[i], wkv, ak[i]);
        }
    }
#pragma unroll
    for (int i = 0; i < 16; ++i) {
        size_t row = (size_t)(rbase + g * 16 + i);
        Qb[row * DD + col] = f2bf(aq[i]);
        Kb[row * DD + col] = f2bf(ak[i]);
    }
    // Hn^T: [b][128][2048]; 16 consecutive n-indices -> 32B contiguous
    int b = rbase >> 11;
    int n0 = (rbase & (NN - 1)) + g * 16;
    u16* hp = HnT + (size_t)b * DD * NN + (size_t)col * NN + n0;
    unsigned pk[8];
#pragma unroll
    for (int i = 0; i < 8; ++i)
        pk[i] = (unsigned)f2bf(ah[2 * i]) | ((unsigned)f2bf(ah[2 * i + 1]) << 16);
    *(uint4*)&hp[0] = make_uint4(pk[0], pk[1], pk[2], pk[3]);
    *(uint4*)&hp[8] = make_uint4(pk[4], pk[5], pk[6], pk[7]);
}

// ---------------- MFMA GEMM: C[m][n] = scale * sum_k A[m][k]*B[n][k] --------
// A: bf16 row-major (or fp32 row-major, converted during staging)
// B: bf16 row-major (N x K). 128x128 block tile, 4 waves 2x2, 4x4 16x16x32.
#define LDT 72   // LDS row stride (u16): 64 + 8 pad -> 16B-aligned frags, no extra conflicts
__global__ __launch_bounds__(256) void mfma_tn_kernel(
        const void* __restrict__ Ap, const u16* __restrict__ Bp,
        float* __restrict__ Cp, int lda, int ldb, int ldc,
        long long sA, long long sB, long long sC, long long sPart,
        int kIters, int ksplit, float scale, int aFp32) {
    __shared__ u16 As[128 * LDT];
    __shared__ u16 Bs[128 * LDT];
    int zb = blockIdx.z / ksplit;
    int ks = blockIdx.z % ksplit;
    int rb = blockIdx.y * 128;
    int cb = blockIdx.x * 128;
    int t = threadIdx.x;
    int lane = t & 63, w = t >> 6;
    int wr = w >> 1, wc = w & 1;
    int q = lane >> 4, r16 = lane & 15;
    int kStart = ks * (kIters * 64);

    const u16* Bb = Bp + (size_t)zb * sB;
    f32x4 acc[4][4];
#pragma unroll
    for (int i = 0; i < 4; ++i)
#pragma unroll
        for (int j = 0; j < 4; ++j)
            acc[i][j] = (f32x4){0.f, 0.f, 0.f, 0.f};

    for (int it = 0; it < kIters; ++it) {
        int kc = kStart + it * 64;
        __syncthreads();
        if (aFp32) {
            const float* A32 = (const float*)Ap + (size_t)zb * sA;
#pragma unroll
            for (int i = 0; i < 8; ++i) {
                int idx = i * 256 + t;
                int row = idx >> 4, seg = idx & 15;
                float4 v = *(const float4*)&A32[(size_t)(rb + row) * lda + kc + seg * 4];
                ushort4 o;
                o.x = f2bf(v.x); o.y = f2bf(v.y); o.z = f2bf(v.z); o.w = f2bf(v.w);
                *(ushort4*)&As[row * LDT + seg * 4] = o;
            }
        } else {
            const u16* A16 = (const u16*)Ap + (size_t)zb * sA;
#pragma unroll
            for (int i = 0; i < 4; ++i) {
                int idx = i * 256 + t;
                int row = idx >> 3, seg = idx & 7;
                uint4 v = *(const uint4*)&A16[(size_t)(rb + row) * lda + kc + seg * 8];
                *(uint4*)&As[row * LDT + seg * 8] = v;
            }
        }
#pragma unroll
        for (int i = 0; i < 4; ++i) {
            int idx = i * 256 + t;
            int row = idx >> 3, seg = idx & 7;
            uint4 v = *(const uint4*)&Bb[(size_t)(cb + row) * ldb + kc + seg * 8];
            *(uint4*)&Bs[row * LDT + seg * 8] = v;
        }
        __syncthreads();
#pragma unroll
        for (int kb = 0; kb < 2; ++kb) {
            int ko = kb * 32 + q * 8;
            bf16x8 af[4], bfr[4];
#pragma unroll
            for (int i = 0; i < 4; ++i)
                af[i] = *(const bf16x8*)&As[(wr * 64 + i * 16 + r16) * LDT + ko];
#pragma unroll
            for (int j = 0; j < 4; ++j)
                bfr[j] = *(const bf16x8*)&Bs[(wc * 64 + j * 16 + r16) * LDT + ko];
#pragma unroll
            for (int i = 0; i < 4; ++i)
#pragma unroll
                for (int j = 0; j < 4; ++j)
                    acc[i][j] = __builtin_amdgcn_mfma_f32_16x16x32_bf16(
                        af[i], bfr[j], acc[i][j], 0, 0, 0);
        }
    }
    // C/D layout: col = lane&15, row = quad*4 + reg  [m89-verified]
    float* Cb = Cp + (size_t)ks * sPart + (size_t)zb * sC;
#pragma unroll
    for (int i = 0; i < 4; ++i) {
        int row = rb + wr * 64 + i * 16 + q * 4;
#pragma unroll
        for (int j = 0; j < 4; ++j) {
            int col = cb + wc * 64 + j * 16 + r16;
#pragma unroll
            for (int r = 0; r < 4; ++r)
                Cb[(size_t)(row + r) * ldc + col] = acc[i][j][r] * scale;
        }
    }
}

// ---------------- K5: per-row bias + mask + softmax + fuse + renormalize ----
__global__ __launch_bounds__(256) void rowfuse_kernel(float* __restrict__ Afuse,
                                                      const float* __restrict__ Astat,
                                                      const int* __restrict__ Mm,
                                                      const float* __restrict__ rel) {
    __shared__ float red[4];
    int bn = blockIdx.x;                          // b*N + n
    int b = bn >> 11;
    int n = bn & (NN - 1);
    int t = threadIdx.x;
    float* Arow = Afuse + (size_t)bn * NN;
    const float* Asrow = Astat + (size_t)n * NN;
    const int* Mrow = Mm + (size_t)n * NN;
    float rn = fminf(fmaxf(rel[bn], 0.f), 1.f);

    float l[8], as[8], rm[8];
    int eg[8];
    float lmax = -1e30f;
#pragma unroll
    for (int i = 0; i < 8; ++i) {
        int m = i * 256 + t;
        float dot = Arow[m];                      // already scaled by 1/sqrt(D)
        float a = Asrow[m];
        as[i] = a;
        int e = Mrow[m];
        eg[i] = e;
        float p = fminf(fmaxf(a, 1e-3f), 1.f - 1e-3f);
        float lg = __logf(p / (1.f - p));         // ETA = 1.0
        l[i] = e ? (dot + lg) : -1e30f;
        lmax = fmaxf(lmax, l[i]);
        rm[i] = fminf(fmaxf(rel[b * NN + m], 0.f), 1.f);
    }
    float v = lmax;
#pragma unroll
    for (int off = 32; off; off >>= 1) v = fmaxf(v, __shfl_down(v, off));
    if ((t & 63) == 0) red[t >> 6] = v;
    __syncthreads();
    float mx = fmaxf(fmaxf(red[0], red[1]), fmaxf(red[2], red[3]));
    __syncthreads();
    float e_[8];
    float esum = 0.f;
#pragma unroll
    for (int i = 0; i < 8; ++i) {
        e_[i] = eg[i] ? __expf(l[i] - mx) : 0.f;
        esum += e_[i];
    }
    v = esum;
#pragma unroll
    for (int off = 32; off; off >>= 1) v += __shfl_down(v, off);
    if ((t & 63) == 0) red[t >> 6] = v;
    __syncthreads();
    float sm = red[0] + red[1] + red[2] + red[3];
    __syncthreads();
    float inv = 1.f / sm;
    float val[8];
    float fsum = 0.f;
#pragma unroll
    for (int i = 0; i < 8; ++i) {
        val[i] = eg[i] ? (0.6f * e_[i] * inv + 0.4f * as[i]) * rn * rm[i] : 0.f;
        fsum += val[i];
    }
    v = fsum;
#pragma unroll
    for (int off = 32; off; off >>= 1) v += __shfl_down(v, off);
    if ((t & 63) == 0) red[t >> 6] = v;
    __syncthreads();
    float fs = red[0] + red[1] + red[2] + red[3];
    float norm = 1.f / (fs + 1e-8f);
#pragma unroll
    for (int i = 0; i < 8; ++i)
        Arow[i * 256 + t] = val[i] * norm;
}

// ---------------- fp32 GEMM (small, W_lin): A may be sum of nsum partials ---
__global__ __launch_bounds__(256) void gemm_nn_kernel(const float* __restrict__ A,
                                                      const float* __restrict__ Bm,
                                                      float* __restrict__ Cm,
                                                      int K, int lda,
                                                      int nsum, long long psum) {
    float* Cb = Cm;
    int rb = blockIdx.y * 64;
    int cb = blockIdx.x * 64;
    __shared__ float At[32 * 68], Bt[32 * 68];    // k-major: [kk*68 + row/col]
    int t = threadIdx.x;
    int tx = t & 15, ty = t >> 4;
    float acc[4][4] = {};

    for (int kc = 0; kc < K; kc += 32) {
        __syncthreads();
#pragma unroll
        for (int i = 0; i < 8; ++i) {
            int idx = i * 256 + t;
            {
                int row = idx >> 5, kk = idx & 31;
                size_t off = (size_t)(rb + row) * lda + kc + kk;
                float a = A[off];
                for (int s = 1; s < nsum; ++s) a += A[off + (size_t)s * psum];
                At[kk * 68 + row] = a;
            }
            {
                int kk = idx >> 6, col = idx & 63;
                Bt[kk * 68 + col] = Bm[(size_t)(kc + kk) * DD + cb + col];
            }
        }
        __syncthreads();
#pragma unroll
        for (int kk = 0; kk < 32; ++kk) {
            float4 av = *(const float4*)&At[kk * 68 + ty * 4];
            float4 bv = *(const float4*)&Bt[kk * 68 + tx * 4];
            float av4[4] = {av.x, av.y, av.z, av.w};
            float bv4[4] = {bv.x, bv.y, bv.z, bv.w};
#pragma unroll
            for (int r = 0; r < 4; ++r)
#pragma unroll
                for (int c = 0; c < 4; ++c)
                    acc[r][c] = fmaf(av4[r], bv4[c], acc[r][c]);
        }
    }
#pragma unroll
    for (int r = 0; r < 4; ++r) {
        float4 o = make_float4(acc[r][0], acc[r][1], acc[r][2], acc[r][3]);
        *(float4*)&Cb[(size_t)(rb + ty * 4 + r) * DD + cb + tx * 4] = o;
    }
}

// ---------------- K8: relu -> LN1 -> LN2 -----------------------------------
__global__ __launch_bounds__(128) void ln_kernel(const float* __restrict__ Hin,
                                                 const float* __restrict__ s1,
                                                 const float* __restrict__ b1,
                                                 const float* __restrict__ s2,
                                                 const float* __restrict__ b2,
                                                 float* __restrict__ out) {
    __shared__ float red[2];
    int row = blockIdx.x;
    int d = threadIdx.x;
    float v = fmaxf(Hin[(size_t)row * DD + d], 0.f);

    auto rsum = [&](float xv) {
#pragma unroll
        for (int off = 32; off; off >>= 1) xv += __shfl_down(xv, off);
        if ((threadIdx.x & 63) == 0) red[threadIdx.x >> 6] = xv;
        __syncthreads();
        float tot = red[0] + red[1];
        __syncthreads();
        return tot;
    };

    float mu = rsum(v) * (1.f / 128.f);
    float dv = v - mu;
    float var = rsum(dv * dv) * (1.f / 128.f);
    float y = dv * (1.f / sqrtf(var + 1e-5f)) * s1[d] + b1[d];
    float mu2 = rsum(y) * (1.f / 128.f);
    float dy = y - mu2;
    float var2 = rsum(dy * dy) * (1.f / 128.f);
    out[(size_t)row * DD + d] = dy * (1.f / sqrtf(var2 + 1e-5f)) * s2[d] + b2[d];
}

extern "C" void kernel_launch(void* const* d_in, const int* in_sizes, int n_in,
                              void* d_out, int out_size, void* d_ws, size_t ws_size,
                              hipStream_t stream) {
    const float* X = (const float*)d_in[0];
    const float* Msk = (const float*)d_in[1];
    const float* Astat = (const float*)d_in[2];
    const int* Mm = (const int*)d_in[3];
    const float* rel = (const float*)d_in[4];
    const float* Wproj = (const float*)d_in[5];
    const float* Wq = (const float*)d_in[6];
    const float* Wk = (const float*)d_in[7];
    const float* Wlin = (const float*)d_in[8];
    const float* s1 = (const float*)d_in[9];
    const float* b1 = (const float*)d_in[10];
    const float* s2 = (const float*)d_in[11];
    const float* b2 = (const float*)d_in[12];

    float* outMain = (float*)d_out;                       // (B,N,D) = 2097152
    float* Afuse = outMain + (size_t)BB * NN * DD;        // (B,N,N) = 33554432

    float* w = (float*)d_ws;
    float* x = w;                                         // 524288 f
    float* Wpq = w + 524288;                              // 4096 f
    float* Wpk = w + 528384;                              // 4096 f
    u16* Qb = (u16*)(w + 532480);                         // 2097152 u16 (1048576 f)
    u16* Kb = (u16*)(w + 1581056);                        // 2097152 u16
    u16* HnT = (u16*)(w + 2629632);                       // 2097152 u16
    float* Hp = w + 3678208;                              // 4 * 2097152 f (partials)
    float* H2 = w + 12066816;                             // 2097152 f

    pool_kernel<<<dim3(2048), dim3(256), 0, stream>>>(X, Msk, x);
    wcomb_kernel<<<dim3(32), dim3(256), 0, stream>>>(Wproj, Wq, Wk, Wpq, Wpk);
    proj3_kernel<<<dim3(512), dim3(256), 0, stream>>>(x, Wproj, Wpq, Wpk, HnT, Qb, Kb);

    // logits = Q @ K^T / sqrt(D)   (bf16 MFMA, direct store into Afuse region)
    mfma_tn_kernel<<<dim3(16, 16, 8), dim3(256), 0, stream>>>(
        Qb, Kb, Afuse, DD, DD, NN,
        (long long)NN * DD, (long long)NN * DD, (long long)NN * NN, 0LL,
        2, 1, 0.08838834764831845f, 0);

    rowfuse_kernel<<<dim3(16384), dim3(256), 0, stream>>>(Afuse, Astat, Mm, rel);

    // H = A_fuse @ Hn  (A fp32 converted in staging; split-K=4 partials)
    mfma_tn_kernel<<<dim3(1, 16, 32), dim3(256), 0, stream>>>(
        Afuse, HnT, Hp, NN, NN, DD,
        (long long)NN * NN, (long long)NN * DD, (long long)NN * DD,
        (long long)BB * NN * DD,
        8, 4, 1.0f, 1);

    // H2 = (sum_s Hp[s]) @ W_lin   (fp32, small)
    gemm_nn_kernel<<<dim3(2, 256, 1), dim3(256), 0, stream>>>(
        Hp, Wlin, H2, DD, DD, 4, (long long)BB * NN * DD);

    ln_kernel<<<dim3(16384), dim3(128), 0, stream>>>(H2, s1, b1, s2, b2, outMain);
}